// Round 1
// baseline (1979.987 us; speedup 1.0000x reference)
//
#include <hip/hip_runtime.h>
#include <cstdint>
#include <cstddef>

// ---------------------------------------------------------------------------
// AttributeAttentionModule: out = softmax((sa@Wq^T+bq)(x@Wk^T+bk)^T/32) (x@Wv^T+bv)
// B=16384, D=3072, H=3, dh=1024.
// Stage 1: cast inputs fp32->bf16 into ws
// Stage 2: fused QKV GEMM (bf16 MFMA 16x16x32, 128x128x64 tiles, global_load_lds)
// Stage 3: per-row tiny attention (1 wave/row)
// ---------------------------------------------------------------------------

typedef __bf16 bf16x8 __attribute__((ext_vector_type(8)));
typedef float f32x4 __attribute__((ext_vector_type(4)));

#define GLOBAL_AS __attribute__((address_space(1)))
#define LDS_AS __attribute__((address_space(3)))

__device__ __forceinline__ void async_load16(const __bf16* g, __bf16* l) {
    __builtin_amdgcn_global_load_lds((const GLOBAL_AS void*)g, (LDS_AS void*)l,
                                     16, 0, 0);
}

#define DIM 3072
#define BROWS 16384

// ---------------------------------------------------------------------------
// fp32 -> bf16 cast, 8 elements/thread (2x float4 load, 1x 16B store)
// ---------------------------------------------------------------------------
__global__ __launch_bounds__(256) void cast_f32_bf16(
    const float* __restrict__ src, __bf16* __restrict__ dst, int n8) {
    int i = blockIdx.x * 256 + threadIdx.x;
    if (i >= n8) return;
    const float4* s4 = reinterpret_cast<const float4*>(src);
    float4 a = s4[2 * i];
    float4 b = s4[2 * i + 1];
    bf16x8 o;
    o[0] = (__bf16)a.x; o[1] = (__bf16)a.y; o[2] = (__bf16)a.z; o[3] = (__bf16)a.w;
    o[4] = (__bf16)b.x; o[5] = (__bf16)b.y; o[6] = (__bf16)b.z; o[7] = (__bf16)b.w;
    *reinterpret_cast<bf16x8*>(dst + (size_t)i * 8) = o;
}

// ---------------------------------------------------------------------------
// Fused QKV GEMM: C = A @ W^T + bias, A row-major [B,D], W row-major [D,D]
// (both K-contiguous). Grid: 128 m-blocks x 72 n-blocks; n-block selects
// projection (0..23 Q, 24..47 K, 48..71 V).
// Block tile 128x128x64; 4 waves in 2x2; each wave 64x64 via 4x4 MFMAs.
// ---------------------------------------------------------------------------
__global__ __launch_bounds__(256) void gemm_qkv(
    const __bf16* __restrict__ xb, const __bf16* __restrict__ sb,
    const __bf16* __restrict__ wqb, const __bf16* __restrict__ wkb,
    const __bf16* __restrict__ wvb,
    const float* __restrict__ bq, const float* __restrict__ bk,
    const float* __restrict__ bv,
    __bf16* __restrict__ qo, __bf16* __restrict__ ko, __bf16* __restrict__ vo) {

    __shared__ __bf16 As[128 * 64];
    __shared__ __bf16 Bs[128 * 64];

    const int tid  = threadIdx.x;
    const int lane = tid & 63;
    const int wave = tid >> 6;
    const int wm   = wave >> 1;   // 0..1
    const int wn   = wave & 1;    // 0..1

    const int bid  = blockIdx.x;
    const int bn   = bid % 72;
    const int bm   = bid / 72;
    const int proj = bn / 24;             // 0=Q 1=K 2=V
    const int n0   = (bn % 24) * 128;
    const int m0   = bm * 128;

    const __bf16* A = (proj == 0) ? sb : xb;
    const __bf16* W = (proj == 0) ? wqb : (proj == 1 ? wkb : wvb);
    const float*  bias = (proj == 0) ? bq : (proj == 1 ? bk : bv);
    __bf16* O = (proj == 0) ? qo : (proj == 1 ? ko : vo);

    const __bf16* Ab = A + (size_t)m0 * DIM;
    const __bf16* Wb = W + (size_t)n0 * DIM;

    // staging addresses: idx = i*256+tid in [0,1024); row=idx>>3, col8=(idx&7)*8
    const __bf16* ag[4];
    const __bf16* wg[4];
    __bf16* al[4];
    __bf16* bl[4];
#pragma unroll
    for (int i = 0; i < 4; ++i) {
        int idx = i * 256 + tid;
        int row = idx >> 3;
        int c8  = (idx & 7) << 3;
        ag[i] = Ab + (size_t)row * DIM + c8;
        wg[i] = Wb + (size_t)row * DIM + c8;
        al[i] = &As[idx * 8];
        bl[i] = &Bs[idx * 8];
    }

    f32x4 acc[4][4];
#pragma unroll
    for (int mt = 0; mt < 4; ++mt)
#pragma unroll
        for (int nt = 0; nt < 4; ++nt)
            acc[mt][nt] = (f32x4){0.f, 0.f, 0.f, 0.f};

    const int lr = lane & 15;
    const int lkbase = (lane >> 4) * 8;

    for (int kt = 0; kt < DIM / 64; ++kt) {
        const int k0 = kt * 64;
#pragma unroll
        for (int i = 0; i < 4; ++i) {
            async_load16(ag[i] + k0, al[i]);
            async_load16(wg[i] + k0, bl[i]);
        }
        __syncthreads();   // drains vmcnt -> LDS tiles valid

#pragma unroll
        for (int kk = 0; kk < 64; kk += 32) {
            const int lk = lkbase + kk;
            bf16x8 af[4], bfv[4];
#pragma unroll
            for (int t = 0; t < 4; ++t)
                af[t] = *reinterpret_cast<const bf16x8*>(
                    &As[(wm * 64 + t * 16 + lr) * 64 + lk]);
#pragma unroll
            for (int t = 0; t < 4; ++t)
                bfv[t] = *reinterpret_cast<const bf16x8*>(
                    &Bs[(wn * 64 + t * 16 + lr) * 64 + lk]);
#pragma unroll
            for (int mt = 0; mt < 4; ++mt)
#pragma unroll
                for (int nt = 0; nt < 4; ++nt)
                    acc[mt][nt] = __builtin_amdgcn_mfma_f32_16x16x32_bf16(
                        af[mt], bfv[nt], acc[mt][nt], 0, 0, 0);
        }
        __syncthreads();   // protect LDS before next stage
    }

    // epilogue: C/D layout col=lane&15, row=(lane>>4)*4+reg
    const int lrow = (lane >> 4) * 4;
#pragma unroll
    for (int nt = 0; nt < 4; ++nt) {
        const int n = n0 + wn * 64 + nt * 16 + lr;
        const float bn_f = bias[n];
#pragma unroll
        for (int mt = 0; mt < 4; ++mt) {
            const int mbase = m0 + wm * 64 + mt * 16 + lrow;
#pragma unroll
            for (int r = 0; r < 4; ++r) {
                O[(size_t)(mbase + r) * DIM + n] =
                    (__bf16)(acc[mt][nt][r] + bn_f);
            }
        }
    }
}

// ---------------------------------------------------------------------------
// Tiny cross-attention: one wave per row. dh=1024 -> lane covers 8 d's per
// half (d = it*512 + lane*8). 9 scores via butterfly reduction.
// ---------------------------------------------------------------------------
__global__ __launch_bounds__(256) void attn_kernel(
    const __bf16* __restrict__ q, const __bf16* __restrict__ k,
    const __bf16* __restrict__ v, float* __restrict__ out) {
    const int wave = threadIdx.x >> 6;
    const int lane = threadIdx.x & 63;
    const size_t b = (size_t)blockIdx.x * 4 + wave;

    const __bf16* qr = q + b * DIM;
    const __bf16* kr = k + b * DIM;
    const __bf16* vr = v + b * DIM;

    float s[3][3] = {{0.f, 0.f, 0.f}, {0.f, 0.f, 0.f}, {0.f, 0.f, 0.f}};

#pragma unroll
    for (int it = 0; it < 2; ++it) {
        const int d0 = it * 512 + lane * 8;
        bf16x8 q8[3], k8[3];
#pragma unroll
        for (int h = 0; h < 3; ++h)
            q8[h] = *reinterpret_cast<const bf16x8*>(qr + h * 1024 + d0);
#pragma unroll
        for (int g = 0; g < 3; ++g)
            k8[g] = *reinterpret_cast<const bf16x8*>(kr + g * 1024 + d0);
#pragma unroll
        for (int h = 0; h < 3; ++h)
#pragma unroll
            for (int g = 0; g < 3; ++g) {
                float acc = 0.f;
#pragma unroll
                for (int j = 0; j < 8; ++j)
                    acc += (float)q8[h][j] * (float)k8[g][j];
                s[h][g] += acc;
            }
    }

    // wave butterfly reduce each of the 9 partial dots
#pragma unroll
    for (int h = 0; h < 3; ++h)
#pragma unroll
        for (int g = 0; g < 3; ++g) {
            float val = s[h][g];
#pragma unroll
            for (int off = 32; off > 0; off >>= 1)
                val += __shfl_xor(val, off, 64);
            s[h][g] = val;
        }

    // softmax over g (scale = 1/sqrt(1024) = 1/32)
    float w[3][3];
    const float scale = 0.03125f;
#pragma unroll
    for (int h = 0; h < 3; ++h) {
        float s0 = s[h][0] * scale, s1 = s[h][1] * scale, s2 = s[h][2] * scale;
        float mx = fmaxf(s0, fmaxf(s1, s2));
        float e0 = __expf(s0 - mx), e1 = __expf(s1 - mx), e2 = __expf(s2 - mx);
        float inv = 1.f / (e0 + e1 + e2);
        w[h][0] = e0 * inv; w[h][1] = e1 * inv; w[h][2] = e2 * inv;
    }

    // out[h,d] = sum_g w[h][g] * V[g,d]
#pragma unroll
    for (int it = 0; it < 2; ++it) {
        const int d0 = it * 512 + lane * 8;
        bf16x8 v8[3];
#pragma unroll
        for (int g = 0; g < 3; ++g)
            v8[g] = *reinterpret_cast<const bf16x8*>(vr + g * 1024 + d0);
#pragma unroll
        for (int h = 0; h < 3; ++h) {
            float o[8];
#pragma unroll
            for (int j = 0; j < 8; ++j)
                o[j] = w[h][0] * (float)v8[0][j] + w[h][1] * (float)v8[1][j] +
                       w[h][2] * (float)v8[2][j];
            float* op = out + b * DIM + h * 1024 + d0;
            float4 lo = {o[0], o[1], o[2], o[3]};
            float4 hi = {o[4], o[5], o[6], o[7]};
            *reinterpret_cast<float4*>(op) = lo;
            *reinterpret_cast<float4*>(op + 4) = hi;
        }
    }
}

// ---------------------------------------------------------------------------
extern "C" void kernel_launch(void* const* d_in, const int* in_sizes, int n_in,
                              void* d_out, int out_size, void* d_ws,
                              size_t ws_size, hipStream_t stream) {
    const float* x  = (const float*)d_in[0];
    const float* sa = (const float*)d_in[1];
    const float* Wq = (const float*)d_in[2];
    const float* bq = (const float*)d_in[3];
    const float* Wk = (const float*)d_in[4];
    const float* bk = (const float*)d_in[5];
    const float* Wv = (const float*)d_in[6];
    const float* bv = (const float*)d_in[7];
    float* out = (float*)d_out;

    const size_t B = BROWS, D = DIM;
    __bf16* ws  = (__bf16*)d_ws;
    __bf16* xb  = ws;              // B*D
    __bf16* sb  = xb + B * D;      // B*D
    __bf16* wqb = sb + B * D;      // D*D
    __bf16* wkb = wqb + D * D;
    __bf16* wvb = wkb + D * D;
    __bf16* qo  = wvb + D * D;     // B*D
    __bf16* ko  = qo + B * D;
    __bf16* vo  = ko + B * D;
    // total: 5*B*D + 3*D*D bf16 = ~534 MB

    const int nBD8 = (int)(B * D / 8);   // 6291456
    const int nDD8 = (int)(D * D / 8);   // 1179648

    cast_f32_bf16<<<nBD8 / 256, 256, 0, stream>>>(x, xb, nBD8);
    cast_f32_bf16<<<nBD8 / 256, 256, 0, stream>>>(sa, sb, nBD8);
    cast_f32_bf16<<<nDD8 / 256, 256, 0, stream>>>(Wq, wqb, nDD8);
    cast_f32_bf16<<<nDD8 / 256, 256, 0, stream>>>(Wk, wkb, nDD8);
    cast_f32_bf16<<<nDD8 / 256, 256, 0, stream>>>(Wv, wvb, nDD8);

    gemm_qkv<<<128 * 72, 256, 0, stream>>>(xb, sb, wqb, wkb, wvb, bq, bk, bv,
                                           qo, ko, vo);

    attn_kernel<<<BROWS / 4, 256, 0, stream>>>(qo, ko, vo, out);
}

// Round 2
// 1847.450 us; speedup vs baseline: 1.0717x; 1.0717x over previous
//
#include <hip/hip_runtime.h>
#include <cstdint>
#include <cstddef>

// ---------------------------------------------------------------------------
// AttributeAttentionModule: out = softmax((sa@Wq^T+bq)(x@Wk^T+bk)^T/32) (x@Wv^T+bv)
// B=16384, D=3072, H=3, dh=1024.
// Stage 1: cast inputs fp32->bf16 into ws
// Stage 2: fused QKV GEMM (bf16 MFMA 16x16x32, 128x128x64 tiles, global_load_lds,
//          XOR-swizzled LDS layout to kill 16-way bank conflicts)
// Stage 3: per-row tiny attention (1 wave/row)
// ---------------------------------------------------------------------------

typedef __bf16 bf16x8 __attribute__((ext_vector_type(8)));
typedef float f32x4 __attribute__((ext_vector_type(4)));

#define GLOBAL_AS __attribute__((address_space(1)))
#define LDS_AS __attribute__((address_space(3)))

__device__ __forceinline__ void async_load16(const __bf16* g, __bf16* l) {
    __builtin_amdgcn_global_load_lds((const GLOBAL_AS void*)g, (LDS_AS void*)l,
                                     16, 0, 0);
}

#define DIM 3072
#define BROWS 16384

// ---------------------------------------------------------------------------
// fp32 -> bf16 cast, 8 elements/thread (2x float4 load, 1x 16B store)
// ---------------------------------------------------------------------------
__global__ __launch_bounds__(256) void cast_f32_bf16(
    const float* __restrict__ src, __bf16* __restrict__ dst, int n8) {
    int i = blockIdx.x * 256 + threadIdx.x;
    if (i >= n8) return;
    const float4* s4 = reinterpret_cast<const float4*>(src);
    float4 a = s4[2 * i];
    float4 b = s4[2 * i + 1];
    bf16x8 o;
    o[0] = (__bf16)a.x; o[1] = (__bf16)a.y; o[2] = (__bf16)a.z; o[3] = (__bf16)a.w;
    o[4] = (__bf16)b.x; o[5] = (__bf16)b.y; o[6] = (__bf16)b.z; o[7] = (__bf16)b.w;
    *reinterpret_cast<bf16x8*>(dst + (size_t)i * 8) = o;
}

// ---------------------------------------------------------------------------
// Fused QKV GEMM: C = A @ W^T + bias, A row-major [B,D], W row-major [D,D]
// (both K-contiguous). Grid: 128 m-blocks x 72 n-blocks; n-block selects
// projection (0..23 Q, 24..47 K, 48..71 V).
// Block tile 128x128x64; 4 waves in 2x2; each wave 64x64 via 4x4 MFMAs.
//
// LDS layout (both tiles): row-major [128][64] bf16, but within each row the
// eight 16B chunks are XOR-swizzled: global chunk c of row r lives at chunk
// position (c ^ (r&7)). Row stride is 128B = one full bank sweep, so without
// the swizzle, fragment reads (16 lanes sharing k, differing in row) pile
// 16 lanes on one 4-bank group (measured 3.4e8 conflict cycles). With it,
// 16 consecutive rows spread over all 8 chunk groups (2-way = free).
// global_load_lds demands contiguous LDS dest per lane, so the swizzle is
// applied by permuting the *global* source chunk each lane fetches.
// ---------------------------------------------------------------------------
__global__ __launch_bounds__(256) void gemm_qkv(
    const __bf16* __restrict__ xb, const __bf16* __restrict__ sb,
    const __bf16* __restrict__ wqb, const __bf16* __restrict__ wkb,
    const __bf16* __restrict__ wvb,
    const float* __restrict__ bq, const float* __restrict__ bk,
    const float* __restrict__ bv,
    __bf16* __restrict__ qo, __bf16* __restrict__ ko, __bf16* __restrict__ vo) {

    __shared__ __bf16 As[128 * 64];
    __shared__ __bf16 Bs[128 * 64];

    const int tid  = threadIdx.x;
    const int lane = tid & 63;
    const int wave = tid >> 6;
    const int wm   = wave >> 1;   // 0..1
    const int wn   = wave & 1;    // 0..1

    const int bid  = blockIdx.x;
    const int bn   = bid % 72;
    const int bm   = bid / 72;
    const int proj = bn / 24;             // 0=Q 1=K 2=V
    const int n0   = (bn % 24) * 128;
    const int m0   = bm * 128;

    const __bf16* A = (proj == 0) ? sb : xb;
    const __bf16* W = (proj == 0) ? wqb : (proj == 1 ? wkb : wvb);
    const float*  bias = (proj == 0) ? bq : (proj == 1 ? bk : bv);
    __bf16* O = (proj == 0) ? qo : (proj == 1 ? ko : vo);

    const __bf16* Ab = A + (size_t)m0 * DIM;
    const __bf16* Wb = W + (size_t)n0 * DIM;

    // staging addresses: idx = i*256+tid in [0,1024); LDS dest = idx*16B
    // contiguous; global source chunk = (idx&7) ^ (row&7)  [XOR swizzle]
    const __bf16* ag[4];
    const __bf16* wg[4];
    __bf16* al[4];
    __bf16* bl[4];
#pragma unroll
    for (int i = 0; i < 4; ++i) {
        int idx = i * 256 + tid;
        int row = idx >> 3;
        int c   = (idx & 7) ^ (row & 7);   // swizzled global chunk
        ag[i] = Ab + (size_t)row * DIM + c * 8;
        wg[i] = Wb + (size_t)row * DIM + c * 8;
        al[i] = &As[idx * 8];
        bl[i] = &Bs[idx * 8];
    }

    f32x4 acc[4][4];
#pragma unroll
    for (int mt = 0; mt < 4; ++mt)
#pragma unroll
        for (int nt = 0; nt < 4; ++nt)
            acc[mt][nt] = (f32x4){0.f, 0.f, 0.f, 0.f};

    const int lr = lane & 15;
    const int lc = lane >> 4;   // k-chunk index base (0..3)

    for (int kt = 0; kt < DIM / 64; ++kt) {
        const int k0 = kt * 64;
#pragma unroll
        for (int i = 0; i < 4; ++i) {
            async_load16(ag[i] + k0, al[i]);
            async_load16(wg[i] + k0, bl[i]);
        }
        __syncthreads();   // drains vmcnt -> LDS tiles valid

#pragma unroll
        for (int kk = 0; kk < 64; kk += 32) {
            const int cch = lc + (kk >> 3);   // global k-chunk 0..7
            bf16x8 af[4], bfv[4];
#pragma unroll
            for (int t = 0; t < 4; ++t) {
                const int r = wm * 64 + t * 16 + lr;
                af[t] = *reinterpret_cast<const bf16x8*>(
                    &As[r * 64 + ((cch ^ (r & 7)) << 3)]);
            }
#pragma unroll
            for (int t = 0; t < 4; ++t) {
                const int r = wn * 64 + t * 16 + lr;
                bfv[t] = *reinterpret_cast<const bf16x8*>(
                    &Bs[r * 64 + ((cch ^ (r & 7)) << 3)]);
            }
#pragma unroll
            for (int mt = 0; mt < 4; ++mt)
#pragma unroll
                for (int nt = 0; nt < 4; ++nt)
                    acc[mt][nt] = __builtin_amdgcn_mfma_f32_16x16x32_bf16(
                        af[mt], bfv[nt], acc[mt][nt], 0, 0, 0);
        }
        __syncthreads();   // protect LDS before next stage
    }

    // epilogue: C/D layout col=lane&15, row=(lane>>4)*4+reg
    const int lrow = (lane >> 4) * 4;
#pragma unroll
    for (int nt = 0; nt < 4; ++nt) {
        const int n = n0 + wn * 64 + nt * 16 + lr;
        const float bn_f = bias[n];
#pragma unroll
        for (int mt = 0; mt < 4; ++mt) {
            const int mbase = m0 + wm * 64 + mt * 16 + lrow;
#pragma unroll
            for (int r = 0; r < 4; ++r) {
                O[(size_t)(mbase + r) * DIM + n] =
                    (__bf16)(acc[mt][nt][r] + bn_f);
            }
        }
    }
}

// ---------------------------------------------------------------------------
// Tiny cross-attention: one wave per row. dh=1024 -> lane covers 8 d's per
// half (d = it*512 + lane*8). 9 scores via butterfly reduction.
// ---------------------------------------------------------------------------
__global__ __launch_bounds__(256) void attn_kernel(
    const __bf16* __restrict__ q, const __bf16* __restrict__ k,
    const __bf16* __restrict__ v, float* __restrict__ out) {
    const int wave = threadIdx.x >> 6;
    const int lane = threadIdx.x & 63;
    const size_t b = (size_t)blockIdx.x * 4 + wave;

    const __bf16* qr = q + b * DIM;
    const __bf16* kr = k + b * DIM;
    const __bf16* vr = v + b * DIM;

    float s[3][3] = {{0.f, 0.f, 0.f}, {0.f, 0.f, 0.f}, {0.f, 0.f, 0.f}};

#pragma unroll
    for (int it = 0; it < 2; ++it) {
        const int d0 = it * 512 + lane * 8;
        bf16x8 q8[3], k8[3];
#pragma unroll
        for (int h = 0; h < 3; ++h)
            q8[h] = *reinterpret_cast<const bf16x8*>(qr + h * 1024 + d0);
#pragma unroll
        for (int g = 0; g < 3; ++g)
            k8[g] = *reinterpret_cast<const bf16x8*>(kr + g * 1024 + d0);
#pragma unroll
        for (int h = 0; h < 3; ++h)
#pragma unroll
            for (int g = 0; g < 3; ++g) {
                float acc = 0.f;
#pragma unroll
                for (int j = 0; j < 8; ++j)
                    acc += (float)q8[h][j] * (float)k8[g][j];
                s[h][g] += acc;
            }
    }

    // wave butterfly reduce each of the 9 partial dots
#pragma unroll
    for (int h = 0; h < 3; ++h)
#pragma unroll
        for (int g = 0; g < 3; ++g) {
            float val = s[h][g];
#pragma unroll
            for (int off = 32; off > 0; off >>= 1)
                val += __shfl_xor(val, off, 64);
            s[h][g] = val;
        }

    // softmax over g (scale = 1/sqrt(1024) = 1/32)
    float w[3][3];
    const float scale = 0.03125f;
#pragma unroll
    for (int h = 0; h < 3; ++h) {
        float s0 = s[h][0] * scale, s1 = s[h][1] * scale, s2 = s[h][2] * scale;
        float mx = fmaxf(s0, fmaxf(s1, s2));
        float e0 = __expf(s0 - mx), e1 = __expf(s1 - mx), e2 = __expf(s2 - mx);
        float inv = 1.f / (e0 + e1 + e2);
        w[h][0] = e0 * inv; w[h][1] = e1 * inv; w[h][2] = e2 * inv;
    }

    // out[h,d] = sum_g w[h][g] * V[g,d]
#pragma unroll
    for (int it = 0; it < 2; ++it) {
        const int d0 = it * 512 + lane * 8;
        bf16x8 v8[3];
#pragma unroll
        for (int g = 0; g < 3; ++g)
            v8[g] = *reinterpret_cast<const bf16x8*>(vr + g * 1024 + d0);
#pragma unroll
        for (int h = 0; h < 3; ++h) {
            float o[8];
#pragma unroll
            for (int j = 0; j < 8; ++j)
                o[j] = w[h][0] * (float)v8[0][j] + w[h][1] * (float)v8[1][j] +
                       w[h][2] * (float)v8[2][j];
            float* op = out + b * DIM + h * 1024 + d0;
            float4 lo = {o[0], o[1], o[2], o[3]};
            float4 hi = {o[4], o[5], o[6], o[7]};
            *reinterpret_cast<float4*>(op) = lo;
            *reinterpret_cast<float4*>(op + 4) = hi;
        }
    }
}

// ---------------------------------------------------------------------------
extern "C" void kernel_launch(void* const* d_in, const int* in_sizes, int n_in,
                              void* d_out, int out_size, void* d_ws,
                              size_t ws_size, hipStream_t stream) {
    const float* x  = (const float*)d_in[0];
    const float* sa = (const float*)d_in[1];
    const float* Wq = (const float*)d_in[2];
    const float* bq = (const float*)d_in[3];
    const float* Wk = (const float*)d_in[4];
    const float* bk = (const float*)d_in[5];
    const float* Wv = (const float*)d_in[6];
    const float* bv = (const float*)d_in[7];
    float* out = (float*)d_out;

    const size_t B = BROWS, D = DIM;
    __bf16* ws  = (__bf16*)d_ws;
    __bf16* xb  = ws;              // B*D
    __bf16* sb  = xb + B * D;      // B*D
    __bf16* wqb = sb + B * D;      // D*D
    __bf16* wkb = wqb + D * D;
    __bf16* wvb = wkb + D * D;
    __bf16* qo  = wvb + D * D;     // B*D
    __bf16* ko  = qo + B * D;
    __bf16* vo  = ko + B * D;
    // total: 5*B*D + 3*D*D bf16 = ~534 MB

    const int nBD8 = (int)(B * D / 8);   // 6291456
    const int nDD8 = (int)(D * D / 8);   // 1179648

    cast_f32_bf16<<<nBD8 / 256, 256, 0, stream>>>(x, xb, nBD8);
    cast_f32_bf16<<<nBD8 / 256, 256, 0, stream>>>(sa, sb, nBD8);
    cast_f32_bf16<<<nDD8 / 256, 256, 0, stream>>>(Wq, wqb, nDD8);
    cast_f32_bf16<<<nDD8 / 256, 256, 0, stream>>>(Wk, wkb, nDD8);
    cast_f32_bf16<<<nDD8 / 256, 256, 0, stream>>>(Wv, wvb, nDD8);

    gemm_qkv<<<128 * 72, 256, 0, stream>>>(xb, sb, wqb, wkb, wvb, bq, bk, bv,
                                           qo, ko, vo);

    attn_kernel<<<BROWS / 4, 256, 0, stream>>>(qo, ko, vo, out);
}